// Round 1
// baseline (762.517 us; speedup 1.0000x reference)
//
#include <hip/hip_runtime.h>
#include <math.h>

static constexpr int IN_CH  = 256;
static constexpr int HD1    = 64;   // HEADS*HID
static constexpr int HEADS  = 4;
static constexpr int OUT_CH = 40;
static constexpr float NEG  = 0.2f;

// ---------------- CSR build ----------------
__global__ __launch_bounds__(256) void k_init(int* __restrict__ counts, int* __restrict__ total, int n) {
    int t = blockIdx.x * blockDim.x + threadIdx.x;
    if (t < n) counts[t] = 1;               // self-loop
    if (t == 0) *total = 0;
}

__global__ __launch_bounds__(256) void k_hist(const int* __restrict__ dst, int* __restrict__ counts, int E) {
    int t = blockIdx.x * blockDim.x + threadIdx.x;
    if (t < E) atomicAdd(&counts[dst[t]], 1);
}

// Segment allocation: order of segments is irrelevant, so atomic bump allocation
// replaces an exclusive scan entirely.
__global__ __launch_bounds__(256) void k_alloc(const int* __restrict__ counts, int* __restrict__ rowstart,
                                               int* __restrict__ cursor, int* __restrict__ total, int n) {
    int t = blockIdx.x * blockDim.x + threadIdx.x;
    if (t < n) {
        int c = counts[t];
        int s = atomicAdd(total, c);
        rowstart[t] = s;
        cursor[t]   = s;
    }
}

__global__ __launch_bounds__(256) void k_scatter(const int* __restrict__ ei, int* __restrict__ cursor,
                                                 int* __restrict__ ssrc, int E, int n) {
    int t = blockIdx.x * blockDim.x + threadIdx.x;
    if (t < E) {
        int s = ei[t];
        int d = ei[E + t];
        int pos = atomicAdd(&cursor[d], 1);
        ssrc[pos] = s;
    } else if (t < E + n) {
        int v = t - E;                      // self-loop
        int pos = atomicAdd(&cursor[v], 1);
        ssrc[pos] = v;
    }
}

// ---------------- Layer 1 node transform: h1 = x @ W1, attention logits ----------------
// One wave per row. W1 (256x64 = 64KB) staged in LDS; x-row held in 4 regs/lane,
// broadcast via constant-lane shfl (readlane). Lane j owns output column j.
__global__ __launch_bounds__(256) void k_xform1(const float* __restrict__ x,
        const float* __restrict__ W1, const float* __restrict__ a_src, const float* __restrict__ a_dst,
        float* __restrict__ h1, float* __restrict__ alsrc, float* __restrict__ aldst, int nrows)
{
    __shared__ float W1s[IN_CH * HD1];      // exactly 65536 B
    #pragma unroll
    for (int i = 0; i < 64; ++i) W1s[i * 256 + threadIdx.x] = W1[i * 256 + threadIdx.x];
    __syncthreads();

    const int lane = threadIdx.x & 63;
    const int wid  = (blockIdx.x * blockDim.x + threadIdx.x) >> 6;
    const int nw   = (gridDim.x * blockDim.x) >> 6;
    const float asv = a_src[lane];          // a_src[head][c], lane = head*16+c
    const float adv = a_dst[lane];

    for (int r = wid; r < nrows; r += nw) {
        const float* xr = x + (size_t)r * IN_CH;
        float x0 = xr[lane], x1 = xr[lane + 64], x2 = xr[lane + 128], x3 = xr[lane + 192];
        float a0 = 0.f, a1 = 0.f, a2 = 0.f, a3 = 0.f;
        #pragma unroll
        for (int t = 0; t < 64; ++t) {
            a0 = fmaf(__shfl(x0, t), W1s[(t      ) * 64 + lane], a0);
            a1 = fmaf(__shfl(x1, t), W1s[(t +  64) * 64 + lane], a1);
            a2 = fmaf(__shfl(x2, t), W1s[(t + 128) * 64 + lane], a2);
            a3 = fmaf(__shfl(x3, t), W1s[(t + 192) * 64 + lane], a3);
        }
        float acc = (a0 + a1) + (a2 + a3);
        h1[(size_t)r * HD1 + lane] = acc;

        float s1 = acc * asv, s2 = acc * adv;
        #pragma unroll
        for (int off = 1; off < 16; off <<= 1) {      // reduce within 16-lane head groups
            s1 += __shfl_xor(s1, off);
            s2 += __shfl_xor(s2, off);
        }
        if ((lane & 15) == 0) {
            alsrc[r * HEADS + (lane >> 4)] = s1;
            aldst[r * HEADS + (lane >> 4)] = s2;
        }
    }
}

// ---------------- Layer 1 aggregation: online segment softmax + weighted sum + bias + ELU ----------------
// One wave per dst node; lane j owns (head=j>>4, c=j&15).
__global__ __launch_bounds__(256) void k_aggr1(const float* __restrict__ h1,
        const float* __restrict__ alsrc, const float* __restrict__ aldst, const float* __restrict__ b1,
        const int* __restrict__ rowstart, const int* __restrict__ counts, const int* __restrict__ ssrc,
        float* __restrict__ hact, int n)
{
    const int wid  = (blockIdx.x * blockDim.x + threadIdx.x) >> 6;
    const int lane = threadIdx.x & 63;
    if (wid >= n) return;
    const int head = lane >> 4;

    const float ad = aldst[wid * HEADS + head];
    const int rs  = rowstart[wid];
    const int cnt = counts[wid];

    float m = -INFINITY, d = 0.f, acc = 0.f;
    for (int i = 0; i < cnt; ++i) {
        int s = ssrc[rs + i];
        float l = alsrc[s * HEADS + head] + ad;
        l = l > 0.f ? l : NEG * l;                    // leaky_relu
        float nm = fmaxf(m, l);
        float sc = __expf(m - nm);                    // first iter: exp(-inf)=0
        float p  = __expf(l - nm);
        d = fmaf(d, sc, p);
        float hv = h1[(size_t)s * HD1 + lane];        // coalesced 256B gather
        acc = fmaf(acc, sc, p * hv);
        m = nm;
    }
    float v = acc / (d + 1e-16f) + b1[lane];
    hact[(size_t)wid * HD1 + lane] = v > 0.f ? v : __expf(v) - 1.f;   // ELU
}

// ---------------- Layer 2 node transform: h2 = hact @ W2 (64->40), logits ----------------
__global__ __launch_bounds__(256) void k_xform2(const float* __restrict__ hin,
        const float* __restrict__ W2, const float* __restrict__ a_src, const float* __restrict__ a_dst,
        float* __restrict__ h2, float* __restrict__ alsrc, float* __restrict__ aldst, int nrows)
{
    __shared__ float W2s[HD1 * OUT_CH];     // 10240 B
    for (int i = threadIdx.x; i < HD1 * OUT_CH; i += 256) W2s[i] = W2[i];
    __syncthreads();

    const int lane = threadIdx.x & 63;
    const int wid  = (blockIdx.x * blockDim.x + threadIdx.x) >> 6;
    const int nw   = (gridDim.x * blockDim.x) >> 6;
    const int j    = lane < OUT_CH ? lane : 0;
    const float asv = a_src[j], adv = a_dst[j];

    for (int r = wid; r < nrows; r += nw) {
        float hv = hin[(size_t)r * HD1 + lane];
        float a0 = 0.f, a1 = 0.f;
        #pragma unroll
        for (int t = 0; t < 64; t += 2) {
            a0 = fmaf(__shfl(hv, t    ), W2s[(t    ) * OUT_CH + j], a0);
            a1 = fmaf(__shfl(hv, t + 1), W2s[(t + 1) * OUT_CH + j], a1);
        }
        float acc = a0 + a1;
        bool act = lane < OUT_CH;
        if (act) h2[(size_t)r * OUT_CH + lane] = acc;
        float s1 = act ? acc * asv : 0.f;
        float s2 = act ? acc * adv : 0.f;
        #pragma unroll
        for (int off = 1; off < 64; off <<= 1) {
            s1 += __shfl_xor(s1, off);
            s2 += __shfl_xor(s2, off);
        }
        if (lane == 0) { alsrc[r] = s1; aldst[r] = s2; }
    }
}

// ---------------- Layer 2 aggregation + bias + log_softmax ----------------
__global__ __launch_bounds__(256) void k_aggr2(const float* __restrict__ h2,
        const float* __restrict__ alsrc, const float* __restrict__ aldst, const float* __restrict__ b2,
        const int* __restrict__ rowstart, const int* __restrict__ counts, const int* __restrict__ ssrc,
        float* __restrict__ out, int n)
{
    const int wid  = (blockIdx.x * blockDim.x + threadIdx.x) >> 6;
    const int lane = threadIdx.x & 63;
    if (wid >= n) return;
    const bool act = lane < OUT_CH;

    const float ad = aldst[wid];
    const int rs  = rowstart[wid];
    const int cnt = counts[wid];

    float m = -INFINITY, d = 0.f, acc = 0.f;
    for (int i = 0; i < cnt; ++i) {
        int s = ssrc[rs + i];
        float l = alsrc[s] + ad;
        l = l > 0.f ? l : NEG * l;
        float nm = fmaxf(m, l);
        float sc = __expf(m - nm);
        float p  = __expf(l - nm);
        d = fmaf(d, sc, p);
        float hv = act ? h2[(size_t)s * OUT_CH + lane] : 0.f;
        acc = fmaf(acc, sc, p * hv);
        m = nm;
    }
    float v = acc / (d + 1e-16f) + (act ? b2[lane] : 0.f);

    // log_softmax over the 40 channels (lanes >= 40 padded with -inf / 0)
    float mv = act ? v : -INFINITY;
    #pragma unroll
    for (int off = 1; off < 64; off <<= 1) mv = fmaxf(mv, __shfl_xor(mv, off));
    float ex = act ? __expf(v - mv) : 0.f;
    #pragma unroll
    for (int off = 1; off < 64; off <<= 1) ex += __shfl_xor(ex, off);
    if (act) out[(size_t)wid * OUT_CH + lane] = v - mv - __logf(ex);
}

extern "C" void kernel_launch(void* const* d_in, const int* in_sizes, int n_in,
                              void* d_out, int out_size, void* d_ws, size_t ws_size,
                              hipStream_t stream) {
    const float* x      = (const float*)d_in[0];
    const int*   ei     = (const int*)d_in[1];      // [2,E] int32: row 0 = src, row 1 = dst
    const float* W1     = (const float*)d_in[2];
    const float* a_src1 = (const float*)d_in[3];
    const float* a_dst1 = (const float*)d_in[4];
    const float* b1     = (const float*)d_in[5];
    const float* W2     = (const float*)d_in[6];
    const float* a_src2 = (const float*)d_in[7];
    const float* a_dst2 = (const float*)d_in[8];
    const float* b2     = (const float*)d_in[9];
    float* out = (float*)d_out;

    const int N = in_sizes[0] / IN_CH;
    const int E = in_sizes[1] / 2;

    char* p = (char*)d_ws;
    auto alloc = [&](size_t bytes) -> void* {
        void* r = (void*)p;
        p += (bytes + 255) & ~(size_t)255;
        return r;
    };
    int*   counts   = (int*)alloc((size_t)N * 4);
    int*   rowstart = (int*)alloc((size_t)N * 4);
    int*   cursor   = (int*)alloc((size_t)N * 4);
    int*   total    = (int*)alloc(4);
    int*   ssrc     = (int*)alloc((size_t)(E + N) * 4);
    float* h1       = (float*)alloc((size_t)N * HD1 * 4);      // reused as h2 (N*40 <= N*64)
    float* alsrc1   = (float*)alloc((size_t)N * HEADS * 4);    // reused as alsrc2
    float* aldst1   = (float*)alloc((size_t)N * HEADS * 4);    // reused as aldst2
    float* hact     = (float*)alloc((size_t)N * HD1 * 4);
    float* h2 = h1; float* alsrc2 = alsrc1; float* aldst2 = aldst1;

    k_init   <<<(N + 255) / 256, 256, 0, stream>>>(counts, total, N);
    k_hist   <<<(E + 255) / 256, 256, 0, stream>>>(ei + E, counts, E);
    k_alloc  <<<(N + 255) / 256, 256, 0, stream>>>(counts, rowstart, cursor, total, N);
    k_scatter<<<(E + N + 255) / 256, 256, 0, stream>>>(ei, cursor, ssrc, E, N);

    k_xform1 <<<512, 256, 0, stream>>>(x, W1, a_src1, a_dst1, h1, alsrc1, aldst1, N);
    k_aggr1  <<<(N * 64 + 255) / 256, 256, 0, stream>>>(h1, alsrc1, aldst1, b1, rowstart, counts, ssrc, hact, N);
    k_xform2 <<<512, 256, 0, stream>>>(hact, W2, a_src2, a_dst2, h2, alsrc2, aldst2, N);
    k_aggr2  <<<(N * 64 + 255) / 256, 256, 0, stream>>>(h2, alsrc2, aldst2, b2, rowstart, counts, ssrc, out, N);
}

// Round 2
// 371.181 us; speedup vs baseline: 2.0543x; 2.0543x over previous
//
#include <hip/hip_runtime.h>
#include <math.h>

static constexpr int IN_CH  = 256;
static constexpr int HD1    = 64;   // HEADS*HID
static constexpr int HEADS  = 4;
static constexpr int OUT_CH = 40;
static constexpr float NEG  = 0.2f;

// ---------------- CSR build ----------------
__global__ __launch_bounds__(256) void k_init(int* __restrict__ counts, int* __restrict__ total, int n) {
    int t = blockIdx.x * blockDim.x + threadIdx.x;
    if (t < n) counts[t] = 1;               // self-loop
    if (t == 0) *total = 0;
}

__global__ __launch_bounds__(256) void k_hist(const int* __restrict__ dst, int* __restrict__ counts, int E) {
    int t = blockIdx.x * blockDim.x + threadIdx.x;
    if (t < E) atomicAdd(&counts[dst[t]], 1);
}

__global__ __launch_bounds__(256) void k_alloc(const int* __restrict__ counts, int* __restrict__ rowstart,
                                               int* __restrict__ cursor, int* __restrict__ total, int n) {
    int t = blockIdx.x * blockDim.x + threadIdx.x;
    if (t < n) {
        int c = counts[t];
        int s = atomicAdd(total, c);
        rowstart[t] = s;
        cursor[t]   = s;
    }
}

__global__ __launch_bounds__(256) void k_scatter(const int* __restrict__ ei, int* __restrict__ cursor,
                                                 int* __restrict__ ssrc, int E, int n) {
    int t = blockIdx.x * blockDim.x + threadIdx.x;
    if (t < E) {
        int s = ei[t];
        int d = ei[E + t];
        int pos = atomicAdd(&cursor[d], 1);
        ssrc[pos] = s;
    } else if (t < E + n) {
        int v = t - E;                      // self-loop
        int pos = atomicAdd(&cursor[v], 1);
        ssrc[pos] = v;
    }
}

// ---------------- Layer 1 transform: h1 = x @ W1  (register-tiled fp32 GEMM) ----------------
// 64 threads/block, 8x8 micro-tile, BM=BN=64. x from global (float4, cache-reused x8),
// W1 staged in LDS in two 32KB phases; 2 ds_read_b128 per k-step : 64 FMAs.
__global__ __launch_bounds__(64) void k_xform1(const float* __restrict__ x,
        const float* __restrict__ W1, float* __restrict__ h1, int n)
{
    __shared__ float Ws[128 * 64];          // 32 KiB
    const int t  = threadIdx.x;
    const int rg = t >> 3, cg = t & 7;
    const int r0 = blockIdx.x * 64 + rg * 8;
    const int c0 = cg * 8;

    float acc[8][8];
    #pragma unroll
    for (int i = 0; i < 8; ++i)
        #pragma unroll
        for (int j = 0; j < 8; ++j) acc[i][j] = 0.f;

    const float4* xr[8];
    #pragma unroll
    for (int rr = 0; rr < 8; ++rr) {
        int r = r0 + rr; if (r > n - 1) r = n - 1;   // clamp (compute garbage, skip store)
        xr[rr] = (const float4*)(x + (size_t)r * IN_CH);
    }

    for (int phase = 0; phase < 2; ++phase) {
        __syncthreads();
        const float4* Wg = (const float4*)(W1 + phase * (128 * 64));
        #pragma unroll
        for (int i = 0; i < 32; ++i) ((float4*)Ws)[i * 64 + t] = Wg[i * 64 + t];
        __syncthreads();
        const int kb4 = phase * 32;          // float4 offset along k within a row

        for (int kq = 0; kq < 32; ++kq) {
            float4 xv[8];
            #pragma unroll
            for (int rr = 0; rr < 8; ++rr) xv[rr] = xr[rr][kb4 + kq];
            #pragma unroll
            for (int kk = 0; kk < 4; ++kk) {
                const float* wrow = Ws + (kq * 4 + kk) * 64 + c0;
                const float4 wa = *(const float4*)(wrow);
                const float4 wb = *(const float4*)(wrow + 4);
                #pragma unroll
                for (int rr = 0; rr < 8; ++rr) {
                    const float xs = (kk == 0) ? xv[rr].x : (kk == 1) ? xv[rr].y
                                   : (kk == 2) ? xv[rr].z : xv[rr].w;
                    acc[rr][0] = fmaf(xs, wa.x, acc[rr][0]);
                    acc[rr][1] = fmaf(xs, wa.y, acc[rr][1]);
                    acc[rr][2] = fmaf(xs, wa.z, acc[rr][2]);
                    acc[rr][3] = fmaf(xs, wa.w, acc[rr][3]);
                    acc[rr][4] = fmaf(xs, wb.x, acc[rr][4]);
                    acc[rr][5] = fmaf(xs, wb.y, acc[rr][5]);
                    acc[rr][6] = fmaf(xs, wb.z, acc[rr][6]);
                    acc[rr][7] = fmaf(xs, wb.w, acc[rr][7]);
                }
            }
        }
    }

    #pragma unroll
    for (int rr = 0; rr < 8; ++rr) {
        const int r = r0 + rr;
        if (r < n) {
            float* hp = h1 + (size_t)r * HD1 + c0;
            *(float4*)(hp)     = make_float4(acc[rr][0], acc[rr][1], acc[rr][2], acc[rr][3]);
            *(float4*)(hp + 4) = make_float4(acc[rr][4], acc[rr][5], acc[rr][6], acc[rr][7]);
        }
    }
}

// ---------------- Layer 1 attention logits: al[r][h] = <h1[r,h,:], a[h,:]> ----------------
__global__ __launch_bounds__(256) void k_logits1(const float* __restrict__ h1,
        const float* __restrict__ a_src, const float* __restrict__ a_dst,
        float* __restrict__ alsrc, float* __restrict__ aldst, int n)
{
    const int tid = blockIdx.x * blockDim.x + threadIdx.x;
    const int r = tid >> 2, hd = tid & 3;
    if (r >= n) return;
    const float4* hp = (const float4*)(h1 + (size_t)r * HD1 + hd * 16);
    const float4* as = (const float4*)(a_src + hd * 16);
    const float4* ad = (const float4*)(a_dst + hd * 16);
    float s1 = 0.f, s2 = 0.f;
    #pragma unroll
    for (int i = 0; i < 4; ++i) {
        const float4 hv = hp[i], av = as[i], dv = ad[i];
        s1 += hv.x * av.x + hv.y * av.y + hv.z * av.z + hv.w * av.w;
        s2 += hv.x * dv.x + hv.y * dv.y + hv.z * dv.z + hv.w * dv.w;
    }
    alsrc[r * HEADS + hd] = s1;
    aldst[r * HEADS + hd] = s2;
}

// ---------------- Layer 1 aggregation: online segment softmax + weighted sum + bias + ELU ----------------
__global__ __launch_bounds__(256) void k_aggr1(const float* __restrict__ h1,
        const float* __restrict__ alsrc, const float* __restrict__ aldst, const float* __restrict__ b1,
        const int* __restrict__ rowstart, const int* __restrict__ counts, const int* __restrict__ ssrc,
        float* __restrict__ hact, int n)
{
    const int wid  = (blockIdx.x * blockDim.x + threadIdx.x) >> 6;
    const int lane = threadIdx.x & 63;
    if (wid >= n) return;
    const int head = lane >> 4;

    const float ad = aldst[wid * HEADS + head];
    const int rs  = rowstart[wid];
    const int cnt = counts[wid];

    float m = -INFINITY, d = 0.f, acc = 0.f;
    for (int i = 0; i < cnt; ++i) {
        int s = ssrc[rs + i];
        float l = alsrc[s * HEADS + head] + ad;
        l = l > 0.f ? l : NEG * l;                    // leaky_relu
        float nm = fmaxf(m, l);
        float sc = __expf(m - nm);                    // first iter: exp(-inf)=0
        float p  = __expf(l - nm);
        d = fmaf(d, sc, p);
        float hv = h1[(size_t)s * HD1 + lane];        // coalesced 256B gather
        acc = fmaf(acc, sc, p * hv);
        m = nm;
    }
    float v = acc / (d + 1e-16f) + b1[lane];
    hact[(size_t)wid * HD1 + lane] = v > 0.f ? v : __expf(v) - 1.f;   // ELU
}

// ---------------- Layer 2 transform: h2 = hact @ W2 (64->40) + fused logits ----------------
// Thread-per-row: 40 fp32 accumulators; W2 (10KB) in LDS, all-lane broadcast reads.
__global__ __launch_bounds__(64) void k_xform2(const float* __restrict__ hin,
        const float* __restrict__ W2, const float* __restrict__ a_src, const float* __restrict__ a_dst,
        float* __restrict__ h2, float* __restrict__ alsrc, float* __restrict__ aldst, int n)
{
    __shared__ float Ws[HD1 * OUT_CH];       // 10240 B
    const int t = threadIdx.x;
    #pragma unroll
    for (int i = 0; i < 10; ++i) ((float4*)Ws)[i * 64 + t] = ((const float4*)W2)[i * 64 + t];
    __syncthreads();

    const int r = blockIdx.x * 64 + t;
    if (r >= n) return;

    float acc[OUT_CH];
    #pragma unroll
    for (int j = 0; j < OUT_CH; ++j) acc[j] = 0.f;

    const float4* hr = (const float4*)(hin + (size_t)r * HD1);
    for (int kq = 0; kq < 16; ++kq) {
        const float4 xv = hr[kq];
        #pragma unroll
        for (int kk = 0; kk < 4; ++kk) {
            const float xs = (kk == 0) ? xv.x : (kk == 1) ? xv.y : (kk == 2) ? xv.z : xv.w;
            const float* wrow = Ws + (kq * 4 + kk) * OUT_CH;
            #pragma unroll
            for (int jq = 0; jq < 10; ++jq) {
                const float4 w = *(const float4*)(wrow + jq * 4);
                acc[jq * 4 + 0] = fmaf(xs, w.x, acc[jq * 4 + 0]);
                acc[jq * 4 + 1] = fmaf(xs, w.y, acc[jq * 4 + 1]);
                acc[jq * 4 + 2] = fmaf(xs, w.z, acc[jq * 4 + 2]);
                acc[jq * 4 + 3] = fmaf(xs, w.w, acc[jq * 4 + 3]);
            }
        }
    }

    float s1 = 0.f, s2 = 0.f;
    float4* h2p = (float4*)(h2 + (size_t)r * OUT_CH);
    #pragma unroll
    for (int jq = 0; jq < 10; ++jq) {
        const float4 v = make_float4(acc[jq*4+0], acc[jq*4+1], acc[jq*4+2], acc[jq*4+3]);
        h2p[jq] = v;
        const float4 av = ((const float4*)a_src)[jq];
        const float4 dv = ((const float4*)a_dst)[jq];
        s1 += v.x * av.x + v.y * av.y + v.z * av.z + v.w * av.w;
        s2 += v.x * dv.x + v.y * dv.y + v.z * dv.z + v.w * dv.w;
    }
    alsrc[r] = s1;
    aldst[r] = s2;
}

// ---------------- Layer 2 aggregation + bias + log_softmax ----------------
__global__ __launch_bounds__(256) void k_aggr2(const float* __restrict__ h2,
        const float* __restrict__ alsrc, const float* __restrict__ aldst, const float* __restrict__ b2,
        const int* __restrict__ rowstart, const int* __restrict__ counts, const int* __restrict__ ssrc,
        float* __restrict__ out, int n)
{
    const int wid  = (blockIdx.x * blockDim.x + threadIdx.x) >> 6;
    const int lane = threadIdx.x & 63;
    if (wid >= n) return;
    const bool act = lane < OUT_CH;

    const float ad = aldst[wid];
    const int rs  = rowstart[wid];
    const int cnt = counts[wid];

    float m = -INFINITY, d = 0.f, acc = 0.f;
    for (int i = 0; i < cnt; ++i) {
        int s = ssrc[rs + i];
        float l = alsrc[s] + ad;
        l = l > 0.f ? l : NEG * l;
        float nm = fmaxf(m, l);
        float sc = __expf(m - nm);
        float p  = __expf(l - nm);
        d = fmaf(d, sc, p);
        float hv = act ? h2[(size_t)s * OUT_CH + lane] : 0.f;
        acc = fmaf(acc, sc, p * hv);
        m = nm;
    }
    float v = acc / (d + 1e-16f) + (act ? b2[lane] : 0.f);

    float mv = act ? v : -INFINITY;
    #pragma unroll
    for (int off = 1; off < 64; off <<= 1) mv = fmaxf(mv, __shfl_xor(mv, off));
    float ex = act ? __expf(v - mv) : 0.f;
    #pragma unroll
    for (int off = 1; off < 64; off <<= 1) ex += __shfl_xor(ex, off);
    if (act) out[(size_t)wid * OUT_CH + lane] = v - mv - __logf(ex);
}

extern "C" void kernel_launch(void* const* d_in, const int* in_sizes, int n_in,
                              void* d_out, int out_size, void* d_ws, size_t ws_size,
                              hipStream_t stream) {
    const float* x      = (const float*)d_in[0];
    const int*   ei     = (const int*)d_in[1];
    const float* W1     = (const float*)d_in[2];
    const float* a_src1 = (const float*)d_in[3];
    const float* a_dst1 = (const float*)d_in[4];
    const float* b1     = (const float*)d_in[5];
    const float* W2     = (const float*)d_in[6];
    const float* a_src2 = (const float*)d_in[7];
    const float* a_dst2 = (const float*)d_in[8];
    const float* b2     = (const float*)d_in[9];
    float* out = (float*)d_out;

    const int N = in_sizes[0] / IN_CH;
    const int E = in_sizes[1] / 2;

    char* p = (char*)d_ws;
    auto alloc = [&](size_t bytes) -> void* {
        void* r = (void*)p;
        p += (bytes + 255) & ~(size_t)255;
        return r;
    };
    int*   counts   = (int*)alloc((size_t)N * 4);
    int*   rowstart = (int*)alloc((size_t)N * 4);
    int*   cursor   = (int*)alloc((size_t)N * 4);
    int*   total    = (int*)alloc(4);
    int*   ssrc     = (int*)alloc((size_t)(E + N) * 4);
    float* h1       = (float*)alloc((size_t)N * HD1 * 4);      // reused as h2 (N*40 <= N*64)
    float* alsrc1   = (float*)alloc((size_t)N * HEADS * 4);    // reused as alsrc2
    float* aldst1   = (float*)alloc((size_t)N * HEADS * 4);    // reused as aldst2
    float* hact     = (float*)alloc((size_t)N * HD1 * 4);
    float* h2 = h1; float* alsrc2 = alsrc1; float* aldst2 = aldst1;

    const int nblk64 = (N + 63) / 64;

    k_init   <<<(N + 255) / 256, 256, 0, stream>>>(counts, total, N);
    k_hist   <<<(E + 255) / 256, 256, 0, stream>>>(ei + E, counts, E);
    k_alloc  <<<(N + 255) / 256, 256, 0, stream>>>(counts, rowstart, cursor, total, N);
    k_scatter<<<(E + N + 255) / 256, 256, 0, stream>>>(ei, cursor, ssrc, E, N);

    k_xform1 <<<nblk64, 64, 0, stream>>>(x, W1, h1, N);
    k_logits1<<<(N * HEADS + 255) / 256, 256, 0, stream>>>(h1, a_src1, a_dst1, alsrc1, aldst1, N);
    k_aggr1  <<<(N * 64 + 255) / 256, 256, 0, stream>>>(h1, alsrc1, aldst1, b1, rowstart, counts, ssrc, hact, N);
    k_xform2 <<<nblk64, 64, 0, stream>>>(hact, W2, a_src2, a_dst2, h2, alsrc2, aldst2, N);
    k_aggr2  <<<(N * 64 + 255) / 256, 256, 0, stream>>>(h2, alsrc2, aldst2, b2, rowstart, counts, ssrc, out, N);
}

// Round 3
// 292.810 us; speedup vs baseline: 2.6041x; 1.2677x over previous
//
#include <hip/hip_runtime.h>
#include <math.h>

static constexpr int IN_CH  = 256;
static constexpr int HD1    = 64;   // HEADS*HID
static constexpr int HEADS  = 4;
static constexpr int OUT_CH = 40;
static constexpr float NEG  = 0.2f;

// ---------------- CSR build ----------------
__global__ __launch_bounds__(256) void k_init(int* __restrict__ counts, int* __restrict__ total, int n) {
    int t = blockIdx.x * blockDim.x + threadIdx.x;
    if (t < n) counts[t] = 1;               // self-loop
    if (t == 0) *total = 0;
}

__global__ __launch_bounds__(256) void k_hist(const int* __restrict__ dst, int* __restrict__ counts, int E) {
    int t = blockIdx.x * blockDim.x + threadIdx.x;
    if (t < E) atomicAdd(&counts[dst[t]], 1);
}

__global__ __launch_bounds__(256) void k_alloc(const int* __restrict__ counts, int* __restrict__ rowstart,
                                               int* __restrict__ cursor, int* __restrict__ total, int n) {
    int t = blockIdx.x * blockDim.x + threadIdx.x;
    if (t < n) {
        int c = counts[t];
        int s = atomicAdd(total, c);
        rowstart[t] = s;
        cursor[t]   = s;
    }
}

__global__ __launch_bounds__(256) void k_scatter(const int* __restrict__ ei, int* __restrict__ cursor,
                                                 int* __restrict__ ssrc, int E, int n) {
    int t = blockIdx.x * blockDim.x + threadIdx.x;
    if (t < E) {
        int s = ei[t];
        int d = ei[E + t];
        int pos = atomicAdd(&cursor[d], 1);
        ssrc[pos] = s;
    } else if (t < E + n) {
        int v = t - E;                      // self-loop
        int pos = atomicAdd(&cursor[v], 1);
        ssrc[pos] = v;
    }
}

// ---------------- Layer 1 transform: h1 = x @ W1 + fused attention logits ----------------
// 64 threads/block, 8x8 micro-tile, BM=BN=64. W1 staged in LDS in two 32KB phases.
// Epilogue: logits via shfl_xor(1) pair-reduce (each thread's 8 cols lie in one head).
__global__ __launch_bounds__(64) void k_xform1(const float* __restrict__ x,
        const float* __restrict__ W1, const float* __restrict__ a_src, const float* __restrict__ a_dst,
        float* __restrict__ h1, float* __restrict__ alsrc, float* __restrict__ aldst, int n)
{
    __shared__ float Ws[128 * 64];          // 32 KiB
    const int t  = threadIdx.x;
    const int rg = t >> 3, cg = t & 7;
    const int r0 = blockIdx.x * 64 + rg * 8;
    const int c0 = cg * 8;

    float acc[8][8];
    #pragma unroll
    for (int i = 0; i < 8; ++i)
        #pragma unroll
        for (int j = 0; j < 8; ++j) acc[i][j] = 0.f;

    const float4* xr[8];
    #pragma unroll
    for (int rr = 0; rr < 8; ++rr) {
        int r = r0 + rr; if (r > n - 1) r = n - 1;   // clamp (compute garbage, skip store)
        xr[rr] = (const float4*)(x + (size_t)r * IN_CH);
    }

    for (int phase = 0; phase < 2; ++phase) {
        __syncthreads();
        const float4* Wg = (const float4*)(W1 + phase * (128 * 64));
        #pragma unroll
        for (int i = 0; i < 32; ++i) ((float4*)Ws)[i * 64 + t] = Wg[i * 64 + t];
        __syncthreads();
        const int kb4 = phase * 32;

        for (int kq = 0; kq < 32; ++kq) {
            float4 xv[8];
            #pragma unroll
            for (int rr = 0; rr < 8; ++rr) xv[rr] = xr[rr][kb4 + kq];
            #pragma unroll
            for (int kk = 0; kk < 4; ++kk) {
                const float* wrow = Ws + (kq * 4 + kk) * 64 + c0;
                const float4 wa = *(const float4*)(wrow);
                const float4 wb = *(const float4*)(wrow + 4);
                #pragma unroll
                for (int rr = 0; rr < 8; ++rr) {
                    const float xs = (kk == 0) ? xv[rr].x : (kk == 1) ? xv[rr].y
                                   : (kk == 2) ? xv[rr].z : xv[rr].w;
                    acc[rr][0] = fmaf(xs, wa.x, acc[rr][0]);
                    acc[rr][1] = fmaf(xs, wa.y, acc[rr][1]);
                    acc[rr][2] = fmaf(xs, wa.z, acc[rr][2]);
                    acc[rr][3] = fmaf(xs, wa.w, acc[rr][3]);
                    acc[rr][4] = fmaf(xs, wb.x, acc[rr][4]);
                    acc[rr][5] = fmaf(xs, wb.y, acc[rr][5]);
                    acc[rr][6] = fmaf(xs, wb.z, acc[rr][6]);
                    acc[rr][7] = fmaf(xs, wb.w, acc[rr][7]);
                }
            }
        }
    }

    float as8[8], ad8[8];
    #pragma unroll
    for (int j = 0; j < 8; ++j) { as8[j] = a_src[c0 + j]; ad8[j] = a_dst[c0 + j]; }
    const int head2 = cg >> 1;             // this thread's 8 cols lie in one head

    #pragma unroll
    for (int rr = 0; rr < 8; ++rr) {
        const int r = r0 + rr;
        float s1 = 0.f, s2 = 0.f;
        #pragma unroll
        for (int j = 0; j < 8; ++j) {
            s1 = fmaf(acc[rr][j], as8[j], s1);
            s2 = fmaf(acc[rr][j], ad8[j], s2);
        }
        s1 += __shfl_xor(s1, 1);
        s2 += __shfl_xor(s2, 1);
        if (r < n) {
            float* hp = h1 + (size_t)r * HD1 + c0;
            *(float4*)(hp)     = make_float4(acc[rr][0], acc[rr][1], acc[rr][2], acc[rr][3]);
            *(float4*)(hp + 4) = make_float4(acc[rr][4], acc[rr][5], acc[rr][6], acc[rr][7]);
            if ((cg & 1) == 0) {
                alsrc[r * HEADS + head2] = s1;
                aldst[r * HEADS + head2] = s2;
            }
        }
    }
}

// ---------------- Layer 1 aggregation: 4 nodes/wave, two-phase segment softmax ----------------
// 16-lane group per node; lane sub owns channels sub*4..sub*4+3 (head = sub>>2).
__global__ __launch_bounds__(256) void k_aggr1(const float* __restrict__ h1,
        const float* __restrict__ alsrc, const float* __restrict__ aldst, const float* __restrict__ b1,
        const int* __restrict__ rowstart, const int* __restrict__ counts, const int* __restrict__ ssrc,
        float* __restrict__ hact, int n)
{
    const int wid  = (blockIdx.x * blockDim.x + threadIdx.x) >> 6;
    const int lane = threadIdx.x & 63;
    const int sub  = lane & 15;
    const int head = sub >> 2;

    int nid = wid * 4 + (lane >> 4);
    const bool valid = nid < n;
    if (!valid) nid = n - 1;

    const int rs  = rowstart[nid];
    const int cnt = valid ? counts[nid] : 0;

    int maxcnt = cnt;                       // wave-uniform loop bound
    maxcnt = max(maxcnt, __shfl_xor(maxcnt, 16));
    maxcnt = max(maxcnt, __shfl_xor(maxcnt, 32));

    // Phase A: node-wide max over (edge, head) pairs. Lane handles head (sub&3),
    // edges (sub>>2) + 4k.
    float m = -1e30f;
    {
        const float adA = aldst[nid * HEADS + (sub & 3)];
        const int npairs = cnt * 4, maxpairs = maxcnt * 4;
        for (int idx = sub; idx < maxpairs; idx += 16) {
            if (idx < npairs) {
                int s = ssrc[rs + (idx >> 2)];
                float l = alsrc[s * HEADS + (sub & 3)] + adA;
                l = l > 0.f ? l : NEG * l;
                m = fmaxf(m, l);
            }
        }
        #pragma unroll
        for (int off = 1; off < 16; off <<= 1) m = fmaxf(m, __shfl_xor(m, off));
    }

    // Phase B: independent iterations, gather h1 as float4.
    const float adB = aldst[nid * HEADS + head];
    float d = 0.f;
    float4 acc = make_float4(0.f, 0.f, 0.f, 0.f);
    #pragma unroll 2
    for (int i = 0; i < maxcnt; ++i) {
        const bool on = i < cnt;
        const int s = on ? ssrc[rs + i] : 0;
        float l = alsrc[s * HEADS + head] + adB;
        l = l > 0.f ? l : NEG * l;
        const float p = on ? __expf(l - m) : 0.f;
        d += p;
        const float4 hv = *(const float4*)(h1 + (size_t)s * HD1 + sub * 4);
        acc.x = fmaf(p, hv.x, acc.x);
        acc.y = fmaf(p, hv.y, acc.y);
        acc.z = fmaf(p, hv.z, acc.z);
        acc.w = fmaf(p, hv.w, acc.w);
    }

    const float inv = 1.f / (d + 1e-16f);
    const float4 bv = *(const float4*)(b1 + sub * 4);
    float4 v;
    v.x = acc.x * inv + bv.x;  v.y = acc.y * inv + bv.y;
    v.z = acc.z * inv + bv.z;  v.w = acc.w * inv + bv.w;
    v.x = v.x > 0.f ? v.x : __expf(v.x) - 1.f;   // ELU
    v.y = v.y > 0.f ? v.y : __expf(v.y) - 1.f;
    v.z = v.z > 0.f ? v.z : __expf(v.z) - 1.f;
    v.w = v.w > 0.f ? v.w : __expf(v.w) - 1.f;
    if (valid) *(float4*)(hact + (size_t)nid * HD1 + sub * 4) = v;
}

// ---------------- Layer 2 transform: h2 = hact @ W2 (64->40) + fused logits ----------------
__global__ __launch_bounds__(64) void k_xform2(const float* __restrict__ hin,
        const float* __restrict__ W2, const float* __restrict__ a_src, const float* __restrict__ a_dst,
        float* __restrict__ h2, float* __restrict__ alsrc, float* __restrict__ aldst, int n)
{
    __shared__ float Ws[HD1 * OUT_CH];       // 10240 B
    const int t = threadIdx.x;
    #pragma unroll
    for (int i = 0; i < 10; ++i) ((float4*)Ws)[i * 64 + t] = ((const float4*)W2)[i * 64 + t];
    __syncthreads();

    const int r = blockIdx.x * 64 + t;
    if (r >= n) return;

    float acc[OUT_CH];
    #pragma unroll
    for (int j = 0; j < OUT_CH; ++j) acc[j] = 0.f;

    const float4* hr = (const float4*)(hin + (size_t)r * HD1);
    for (int kq = 0; kq < 16; ++kq) {
        const float4 xv = hr[kq];
        #pragma unroll
        for (int kk = 0; kk < 4; ++kk) {
            const float xs = (kk == 0) ? xv.x : (kk == 1) ? xv.y : (kk == 2) ? xv.z : xv.w;
            const float* wrow = Ws + (kq * 4 + kk) * OUT_CH;
            #pragma unroll
            for (int jq = 0; jq < 10; ++jq) {
                const float4 w = *(const float4*)(wrow + jq * 4);
                acc[jq * 4 + 0] = fmaf(xs, w.x, acc[jq * 4 + 0]);
                acc[jq * 4 + 1] = fmaf(xs, w.y, acc[jq * 4 + 1]);
                acc[jq * 4 + 2] = fmaf(xs, w.z, acc[jq * 4 + 2]);
                acc[jq * 4 + 3] = fmaf(xs, w.w, acc[jq * 4 + 3]);
            }
        }
    }

    float s1 = 0.f, s2 = 0.f;
    float4* h2p = (float4*)(h2 + (size_t)r * OUT_CH);
    #pragma unroll
    for (int jq = 0; jq < 10; ++jq) {
        const float4 v = make_float4(acc[jq*4+0], acc[jq*4+1], acc[jq*4+2], acc[jq*4+3]);
        h2p[jq] = v;
        const float4 av = ((const float4*)a_src)[jq];
        const float4 dv = ((const float4*)a_dst)[jq];
        s1 += v.x * av.x + v.y * av.y + v.z * av.z + v.w * av.w;
        s2 += v.x * dv.x + v.y * dv.y + v.z * dv.z + v.w * dv.w;
    }
    alsrc[r] = s1;
    aldst[r] = s2;
}

// ---------------- Layer 2 aggregation: 4 nodes/wave + bias + log_softmax ----------------
__global__ __launch_bounds__(256) void k_aggr2(const float* __restrict__ h2,
        const float* __restrict__ alsrc, const float* __restrict__ aldst, const float* __restrict__ b2,
        const int* __restrict__ rowstart, const int* __restrict__ counts, const int* __restrict__ ssrc,
        float* __restrict__ out, int n)
{
    const int wid  = (blockIdx.x * blockDim.x + threadIdx.x) >> 6;
    const int lane = threadIdx.x & 63;
    const int sub  = lane & 15;
    const bool act = sub < 10;              // 10 float4 = 40 channels
    const int subc = act ? sub : 0;

    int nid = wid * 4 + (lane >> 4);
    const bool valid = nid < n;
    if (!valid) nid = n - 1;

    const int rs  = rowstart[nid];
    const int cnt = valid ? counts[nid] : 0;

    int maxcnt = cnt;
    maxcnt = max(maxcnt, __shfl_xor(maxcnt, 16));
    maxcnt = max(maxcnt, __shfl_xor(maxcnt, 32));

    const float ad = aldst[nid];

    // Phase A: max over edges, lanes parallel (e = sub + 16k).
    float m = -1e30f;
    for (int e = sub; e < maxcnt; e += 16) {
        if (e < cnt) {
            int s = ssrc[rs + e];
            float l = alsrc[s] + ad;
            l = l > 0.f ? l : NEG * l;
            m = fmaxf(m, l);
        }
    }
    #pragma unroll
    for (int off = 1; off < 16; off <<= 1) m = fmaxf(m, __shfl_xor(m, off));

    // Phase B: independent iterations.
    float d = 0.f;
    float4 acc = make_float4(0.f, 0.f, 0.f, 0.f);
    #pragma unroll 2
    for (int i = 0; i < maxcnt; ++i) {
        const bool on = i < cnt;
        const int s = on ? ssrc[rs + i] : 0;
        float l = alsrc[s] + ad;
        l = l > 0.f ? l : NEG * l;
        const float p = on ? __expf(l - m) : 0.f;
        d += p;
        const float4 hv = *(const float4*)(h2 + (size_t)s * OUT_CH + subc * 4);
        acc.x = fmaf(p, hv.x, acc.x);
        acc.y = fmaf(p, hv.y, acc.y);
        acc.z = fmaf(p, hv.z, acc.z);
        acc.w = fmaf(p, hv.w, acc.w);
    }

    const float inv = 1.f / (d + 1e-16f);
    const float4 bv = *(const float4*)(b2 + subc * 4);
    float4 v;
    v.x = acc.x * inv + bv.x;  v.y = acc.y * inv + bv.y;
    v.z = acc.z * inv + bv.z;  v.w = acc.w * inv + bv.w;

    // log_softmax over 40 channels within the 16-lane group
    float mv = act ? fmaxf(fmaxf(v.x, v.y), fmaxf(v.z, v.w)) : -1e30f;
    #pragma unroll
    for (int off = 1; off < 16; off <<= 1) mv = fmaxf(mv, __shfl_xor(mv, off));
    float ex = act ? (__expf(v.x - mv) + __expf(v.y - mv) + __expf(v.z - mv) + __expf(v.w - mv)) : 0.f;
    #pragma unroll
    for (int off = 1; off < 16; off <<= 1) ex += __shfl_xor(ex, off);
    const float lse = mv + __logf(ex);

    if (valid && act) {
        *(float4*)(out + (size_t)nid * OUT_CH + sub * 4) =
            make_float4(v.x - lse, v.y - lse, v.z - lse, v.w - lse);
    }
}

extern "C" void kernel_launch(void* const* d_in, const int* in_sizes, int n_in,
                              void* d_out, int out_size, void* d_ws, size_t ws_size,
                              hipStream_t stream) {
    const float* x      = (const float*)d_in[0];
    const int*   ei     = (const int*)d_in[1];
    const float* W1     = (const float*)d_in[2];
    const float* a_src1 = (const float*)d_in[3];
    const float* a_dst1 = (const float*)d_in[4];
    const float* b1     = (const float*)d_in[5];
    const float* W2     = (const float*)d_in[6];
    const float* a_src2 = (const float*)d_in[7];
    const float* a_dst2 = (const float*)d_in[8];
    const float* b2     = (const float*)d_in[9];
    float* out = (float*)d_out;

    const int N = in_sizes[0] / IN_CH;
    const int E = in_sizes[1] / 2;

    char* p = (char*)d_ws;
    auto alloc = [&](size_t bytes) -> void* {
        void* r = (void*)p;
        p += (bytes + 255) & ~(size_t)255;
        return r;
    };
    int*   counts   = (int*)alloc((size_t)N * 4);
    int*   rowstart = (int*)alloc((size_t)N * 4);
    int*   cursor   = (int*)alloc((size_t)N * 4);
    int*   total    = (int*)alloc(4);
    int*   ssrc     = (int*)alloc((size_t)(E + N) * 4);
    float* h1       = (float*)alloc((size_t)N * HD1 * 4);      // reused as h2
    float* alsrc1   = (float*)alloc((size_t)N * HEADS * 4);    // reused as alsrc2
    float* aldst1   = (float*)alloc((size_t)N * HEADS * 4);    // reused as aldst2
    float* hact     = (float*)alloc((size_t)N * HD1 * 4);
    float* h2 = h1; float* alsrc2 = alsrc1; float* aldst2 = aldst1;

    const int nblk64 = (N + 63) / 64;
    const int nblkAg = (N + 15) / 16;       // 4 nodes/wave, 4 waves/block

    k_init   <<<(N + 255) / 256, 256, 0, stream>>>(counts, total, N);
    k_hist   <<<(E + 255) / 256, 256, 0, stream>>>(ei + E, counts, E);
    k_alloc  <<<(N + 255) / 256, 256, 0, stream>>>(counts, rowstart, cursor, total, N);
    k_scatter<<<(E + N + 255) / 256, 256, 0, stream>>>(ei, cursor, ssrc, E, N);

    k_xform1 <<<nblk64, 64, 0, stream>>>(x, W1, a_src1, a_dst1, h1, alsrc1, aldst1, N);
    k_aggr1  <<<nblkAg, 256, 0, stream>>>(h1, alsrc1, aldst1, b1, rowstart, counts, ssrc, hact, N);
    k_xform2 <<<nblk64, 64, 0, stream>>>(hact, W2, a_src2, a_dst2, h2, alsrc2, aldst2, N);
    k_aggr2  <<<nblkAg, 256, 0, stream>>>(h2, alsrc2, aldst2, b2, rowstart, counts, ssrc, out, N);
}

// Round 4
// 266.014 us; speedup vs baseline: 2.8665x; 1.1007x over previous
//
#include <hip/hip_runtime.h>
#include <math.h>

static constexpr int IN_CH  = 256;
static constexpr int HD1    = 64;   // HEADS*HID
static constexpr int HEADS  = 4;
static constexpr int OUT_CH = 40;
static constexpr float NEG  = 0.2f;

// ---------------- CSR build ----------------
__global__ __launch_bounds__(256) void k_init(int* __restrict__ counts, int* __restrict__ total, int n) {
    int t = blockIdx.x * blockDim.x + threadIdx.x;
    if (t < n) counts[t] = 1;               // self-loop
    if (t == 0) *total = 0;
}

__global__ __launch_bounds__(256) void k_hist(const int* __restrict__ dst, int* __restrict__ counts, int E) {
    int t = blockIdx.x * blockDim.x + threadIdx.x;
    if (t < E) atomicAdd(&counts[dst[t]], 1);
}

__global__ __launch_bounds__(256) void k_alloc(const int* __restrict__ counts, int* __restrict__ rowstart,
                                               int* __restrict__ cursor, int* __restrict__ total, int n) {
    int t = blockIdx.x * blockDim.x + threadIdx.x;
    if (t < n) {
        int c = counts[t];
        int s = atomicAdd(total, c);
        rowstart[t] = s;
        cursor[t]   = s;
    }
}

__global__ __launch_bounds__(256) void k_scatter(const int* __restrict__ ei, int* __restrict__ cursor,
                                                 int* __restrict__ ssrc, int E, int n) {
    int t = blockIdx.x * blockDim.x + threadIdx.x;
    if (t < E) {
        int s = ei[t];
        int d = ei[E + t];
        int pos = atomicAdd(&cursor[d], 1);
        ssrc[pos] = s;
    } else if (t < E + n) {
        int v = t - E;                      // self-loop
        int pos = atomicAdd(&cursor[v], 1);
        ssrc[pos] = v;
    }
}

// ---------------- Layer 1 transform: h1 = x @ W1 + fused attention logits ----------------
// 128 threads/block (2 waves), 8 rows x 4 cols per thread, BM=BN=64.
// W1 staged in LDS in two 32KB phases; 1 ds_read_b128 : 32 FMAs per k-step.
// Grid 782 blocks -> 1564 waves (~6/CU) vs R2's 782 single-wave blocks (~3/CU).
__global__ __launch_bounds__(128) void k_xform1(const float* __restrict__ x,
        const float* __restrict__ W1, const float* __restrict__ a_src, const float* __restrict__ a_dst,
        float* __restrict__ h1, float* __restrict__ alsrc, float* __restrict__ aldst, int n)
{
    __shared__ float Ws[128 * 64];          // 32 KiB
    const int t  = threadIdx.x;             // 0..127
    const int cg = t & 15;                  // 16 col-groups x 4 cols
    const int rg = t >> 4;                  // 8 row-groups x 8 rows
    const int r0 = blockIdx.x * 64 + rg * 8;
    const int c0 = cg * 4;

    float acc[8][4];
    #pragma unroll
    for (int i = 0; i < 8; ++i)
        #pragma unroll
        for (int j = 0; j < 4; ++j) acc[i][j] = 0.f;

    const float4* xr[8];
    #pragma unroll
    for (int rr = 0; rr < 8; ++rr) {
        int r = r0 + rr; if (r > n - 1) r = n - 1;   // clamp (compute garbage, skip store)
        xr[rr] = (const float4*)(x + (size_t)r * IN_CH);
    }

    for (int phase = 0; phase < 2; ++phase) {
        __syncthreads();
        const float4* Wg = (const float4*)(W1 + phase * (128 * 64));
        #pragma unroll
        for (int i = 0; i < 16; ++i) ((float4*)Ws)[i * 128 + t] = Wg[i * 128 + t];
        __syncthreads();
        const int kb4 = phase * 32;

        for (int kq = 0; kq < 32; ++kq) {
            float4 xv[8];
            #pragma unroll
            for (int rr = 0; rr < 8; ++rr) xv[rr] = xr[rr][kb4 + kq];
            #pragma unroll
            for (int kk = 0; kk < 4; ++kk) {
                const float4 w = *(const float4*)(Ws + (kq * 4 + kk) * 64 + c0);
                #pragma unroll
                for (int rr = 0; rr < 8; ++rr) {
                    const float xs = (kk == 0) ? xv[rr].x : (kk == 1) ? xv[rr].y
                                   : (kk == 2) ? xv[rr].z : xv[rr].w;
                    acc[rr][0] = fmaf(xs, w.x, acc[rr][0]);
                    acc[rr][1] = fmaf(xs, w.y, acc[rr][1]);
                    acc[rr][2] = fmaf(xs, w.z, acc[rr][2]);
                    acc[rr][3] = fmaf(xs, w.w, acc[rr][3]);
                }
            }
        }
    }

    // Fused attention logits: this thread's 4 cols lie in head (cg>>2);
    // reduce across the 4 col-group lanes of the head via shfl_xor(1),(2).
    float as4[4], ad4[4];
    #pragma unroll
    for (int j = 0; j < 4; ++j) { as4[j] = a_src[c0 + j]; ad4[j] = a_dst[c0 + j]; }
    const int head = cg >> 2;

    #pragma unroll
    for (int rr = 0; rr < 8; ++rr) {
        const int r = r0 + rr;
        float s1 = 0.f, s2 = 0.f;
        #pragma unroll
        for (int j = 0; j < 4; ++j) {
            s1 = fmaf(acc[rr][j], as4[j], s1);
            s2 = fmaf(acc[rr][j], ad4[j], s2);
        }
        s1 += __shfl_xor(s1, 1); s1 += __shfl_xor(s1, 2);
        s2 += __shfl_xor(s2, 1); s2 += __shfl_xor(s2, 2);
        if (r < n) {
            *(float4*)(h1 + (size_t)r * HD1 + c0) =
                make_float4(acc[rr][0], acc[rr][1], acc[rr][2], acc[rr][3]);
            if ((cg & 3) == 0) {
                alsrc[r * HEADS + head] = s1;
                aldst[r * HEADS + head] = s2;
            }
        }
    }
}

// ---------------- Layer 1 aggregation: 4 nodes/wave, two-phase segment softmax ----------------
__global__ __launch_bounds__(256) void k_aggr1(const float* __restrict__ h1,
        const float* __restrict__ alsrc, const float* __restrict__ aldst, const float* __restrict__ b1,
        const int* __restrict__ rowstart, const int* __restrict__ counts, const int* __restrict__ ssrc,
        float* __restrict__ hact, int n)
{
    const int wid  = (blockIdx.x * blockDim.x + threadIdx.x) >> 6;
    const int lane = threadIdx.x & 63;
    const int sub  = lane & 15;
    const int head = sub >> 2;

    int nid = wid * 4 + (lane >> 4);
    const bool valid = nid < n;
    if (!valid) nid = n - 1;

    const int rs  = rowstart[nid];
    const int cnt = valid ? counts[nid] : 0;

    int maxcnt = cnt;                       // wave-uniform loop bound
    maxcnt = max(maxcnt, __shfl_xor(maxcnt, 16));
    maxcnt = max(maxcnt, __shfl_xor(maxcnt, 32));

    // Phase A: node-wide max over (edge, head) pairs.
    float m = -1e30f;
    {
        const float adA = aldst[nid * HEADS + (sub & 3)];
        const int npairs = cnt * 4, maxpairs = maxcnt * 4;
        for (int idx = sub; idx < maxpairs; idx += 16) {
            if (idx < npairs) {
                int s = ssrc[rs + (idx >> 2)];
                float l = alsrc[s * HEADS + (sub & 3)] + adA;
                l = l > 0.f ? l : NEG * l;
                m = fmaxf(m, l);
            }
        }
        #pragma unroll
        for (int off = 1; off < 16; off <<= 1) m = fmaxf(m, __shfl_xor(m, off));
    }

    // Phase B: independent iterations, gather h1 as float4.
    const float adB = aldst[nid * HEADS + head];
    float d = 0.f;
    float4 acc = make_float4(0.f, 0.f, 0.f, 0.f);
    #pragma unroll 2
    for (int i = 0; i < maxcnt; ++i) {
        const bool on = i < cnt;
        const int s = on ? ssrc[rs + i] : 0;
        float l = alsrc[s * HEADS + head] + adB;
        l = l > 0.f ? l : NEG * l;
        const float p = on ? __expf(l - m) : 0.f;
        d += p;
        const float4 hv = *(const float4*)(h1 + (size_t)s * HD1 + sub * 4);
        acc.x = fmaf(p, hv.x, acc.x);
        acc.y = fmaf(p, hv.y, acc.y);
        acc.z = fmaf(p, hv.z, acc.z);
        acc.w = fmaf(p, hv.w, acc.w);
    }

    const float inv = 1.f / (d + 1e-16f);
    const float4 bv = *(const float4*)(b1 + sub * 4);
    float4 v;
    v.x = acc.x * inv + bv.x;  v.y = acc.y * inv + bv.y;
    v.z = acc.z * inv + bv.z;  v.w = acc.w * inv + bv.w;
    v.x = v.x > 0.f ? v.x : __expf(v.x) - 1.f;   // ELU
    v.y = v.y > 0.f ? v.y : __expf(v.y) - 1.f;
    v.z = v.z > 0.f ? v.z : __expf(v.z) - 1.f;
    v.w = v.w > 0.f ? v.w : __expf(v.w) - 1.f;
    if (valid) *(float4*)(hact + (size_t)nid * HD1 + sub * 4) = v;
}

// ---------------- Layer 2 transform: h2 = hact @ W2 (64->40) + fused logits ----------------
__global__ __launch_bounds__(64) void k_xform2(const float* __restrict__ hin,
        const float* __restrict__ W2, const float* __restrict__ a_src, const float* __restrict__ a_dst,
        float* __restrict__ h2, float* __restrict__ alsrc, float* __restrict__ aldst, int n)
{
    __shared__ float Ws[HD1 * OUT_CH];       // 10240 B
    const int t = threadIdx.x;
    #pragma unroll
    for (int i = 0; i < 10; ++i) ((float4*)Ws)[i * 64 + t] = ((const float4*)W2)[i * 64 + t];
    __syncthreads();

    const int r = blockIdx.x * 64 + t;
    if (r >= n) return;

    float acc[OUT_CH];
    #pragma unroll
    for (int j = 0; j < OUT_CH; ++j) acc[j] = 0.f;

    const float4* hr = (const float4*)(hin + (size_t)r * HD1);
    for (int kq = 0; kq < 16; ++kq) {
        const float4 xv = hr[kq];
        #pragma unroll
        for (int kk = 0; kk < 4; ++kk) {
            const float xs = (kk == 0) ? xv.x : (kk == 1) ? xv.y : (kk == 2) ? xv.z : xv.w;
            const float* wrow = Ws + (kq * 4 + kk) * OUT_CH;
            #pragma unroll
            for (int jq = 0; jq < 10; ++jq) {
                const float4 w = *(const float4*)(wrow + jq * 4);
                acc[jq * 4 + 0] = fmaf(xs, w.x, acc[jq * 4 + 0]);
                acc[jq * 4 + 1] = fmaf(xs, w.y, acc[jq * 4 + 1]);
                acc[jq * 4 + 2] = fmaf(xs, w.z, acc[jq * 4 + 2]);
                acc[jq * 4 + 3] = fmaf(xs, w.w, acc[jq * 4 + 3]);
            }
        }
    }

    float s1 = 0.f, s2 = 0.f;
    float4* h2p = (float4*)(h2 + (size_t)r * OUT_CH);
    #pragma unroll
    for (int jq = 0; jq < 10; ++jq) {
        const float4 v = make_float4(acc[jq*4+0], acc[jq*4+1], acc[jq*4+2], acc[jq*4+3]);
        h2p[jq] = v;
        const float4 av = ((const float4*)a_src)[jq];
        const float4 dv = ((const float4*)a_dst)[jq];
        s1 += v.x * av.x + v.y * av.y + v.z * av.z + v.w * av.w;
        s2 += v.x * dv.x + v.y * dv.y + v.z * dv.z + v.w * dv.w;
    }
    alsrc[r] = s1;
    aldst[r] = s2;
}

// ---------------- Layer 2 aggregation: 4 nodes/wave + bias + log_softmax ----------------
__global__ __launch_bounds__(256) void k_aggr2(const float* __restrict__ h2,
        const float* __restrict__ alsrc, const float* __restrict__ aldst, const float* __restrict__ b2,
        const int* __restrict__ rowstart, const int* __restrict__ counts, const int* __restrict__ ssrc,
        float* __restrict__ out, int n)
{
    const int wid  = (blockIdx.x * blockDim.x + threadIdx.x) >> 6;
    const int lane = threadIdx.x & 63;
    const int sub  = lane & 15;
    const bool act = sub < 10;              // 10 float4 = 40 channels
    const int subc = act ? sub : 0;

    int nid = wid * 4 + (lane >> 4);
    const bool valid = nid < n;
    if (!valid) nid = n - 1;

    const int rs  = rowstart[nid];
    const int cnt = valid ? counts[nid] : 0;

    int maxcnt = cnt;
    maxcnt = max(maxcnt, __shfl_xor(maxcnt, 16));
    maxcnt = max(maxcnt, __shfl_xor(maxcnt, 32));

    const float ad = aldst[nid];

    // Phase A: max over edges, lanes parallel (e = sub + 16k).
    float m = -1e30f;
    for (int e = sub; e < maxcnt; e += 16) {
        if (e < cnt) {
            int s = ssrc[rs + e];
            float l = alsrc[s] + ad;
            l = l > 0.f ? l : NEG * l;
            m = fmaxf(m, l);
        }
    }
    #pragma unroll
    for (int off = 1; off < 16; off <<= 1) m = fmaxf(m, __shfl_xor(m, off));

    // Phase B: independent iterations.
    float d = 0.f;
    float4 acc = make_float4(0.f, 0.f, 0.f, 0.f);
    #pragma unroll 2
    for (int i = 0; i < maxcnt; ++i) {
        const bool on = i < cnt;
        const int s = on ? ssrc[rs + i] : 0;
        float l = alsrc[s] + ad;
        l = l > 0.f ? l : NEG * l;
        const float p = on ? __expf(l - m) : 0.f;
        d += p;
        const float4 hv = *(const float4*)(h2 + (size_t)s * OUT_CH + subc * 4);
        acc.x = fmaf(p, hv.x, acc.x);
        acc.y = fmaf(p, hv.y, acc.y);
        acc.z = fmaf(p, hv.z, acc.z);
        acc.w = fmaf(p, hv.w, acc.w);
    }

    const float inv = 1.f / (d + 1e-16f);
    const float4 bv = *(const float4*)(b2 + subc * 4);
    float4 v;
    v.x = acc.x * inv + bv.x;  v.y = acc.y * inv + bv.y;
    v.z = acc.z * inv + bv.z;  v.w = acc.w * inv + bv.w;

    // log_softmax over 40 channels within the 16-lane group
    float mv = act ? fmaxf(fmaxf(v.x, v.y), fmaxf(v.z, v.w)) : -1e30f;
    #pragma unroll
    for (int off = 1; off < 16; off <<= 1) mv = fmaxf(mv, __shfl_xor(mv, off));
    float ex = act ? (__expf(v.x - mv) + __expf(v.y - mv) + __expf(v.z - mv) + __expf(v.w - mv)) : 0.f;
    #pragma unroll
    for (int off = 1; off < 16; off <<= 1) ex += __shfl_xor(ex, off);
    const float lse = mv + __logf(ex);

    if (valid && act) {
        *(float4*)(out + (size_t)nid * OUT_CH + sub * 4) =
            make_float4(v.x - lse, v.y - lse, v.z - lse, v.w - lse);
    }
}

extern "C" void kernel_launch(void* const* d_in, const int* in_sizes, int n_in,
                              void* d_out, int out_size, void* d_ws, size_t ws_size,
                              hipStream_t stream) {
    const float* x      = (const float*)d_in[0];
    const int*   ei     = (const int*)d_in[1];
    const float* W1     = (const float*)d_in[2];
    const float* a_src1 = (const float*)d_in[3];
    const float* a_dst1 = (const float*)d_in[4];
    const float* b1     = (const float*)d_in[5];
    const float* W2     = (const float*)d_in[6];
    const float* a_src2 = (const float*)d_in[7];
    const float* a_dst2 = (const float*)d_in[8];
    const float* b2     = (const float*)d_in[9];
    float* out = (float*)d_out;

    const int N = in_sizes[0] / IN_CH;
    const int E = in_sizes[1] / 2;

    char* p = (char*)d_ws;
    auto alloc = [&](size_t bytes) -> void* {
        void* r = (void*)p;
        p += (bytes + 255) & ~(size_t)255;
        return r;
    };
    int*   counts   = (int*)alloc((size_t)N * 4);
    int*   rowstart = (int*)alloc((size_t)N * 4);
    int*   cursor   = (int*)alloc((size_t)N * 4);
    int*   total    = (int*)alloc(4);
    int*   ssrc     = (int*)alloc((size_t)(E + N) * 4);
    float* h1       = (float*)alloc((size_t)N * HD1 * 4);      // reused as h2
    float* alsrc1   = (float*)alloc((size_t)N * HEADS * 4);    // reused as alsrc2
    float* aldst1   = (float*)alloc((size_t)N * HEADS * 4);    // reused as aldst2
    float* hact     = (float*)alloc((size_t)N * HD1 * 4);
    float* h2 = h1; float* alsrc2 = alsrc1; float* aldst2 = aldst1;

    const int nblk64 = (N + 63) / 64;
    const int nblkAg = (N + 15) / 16;       // 4 nodes/wave, 4 waves/block

    k_init   <<<(N + 255) / 256, 256, 0, stream>>>(counts, total, N);
    k_hist   <<<(E + 255) / 256, 256, 0, stream>>>(ei + E, counts, E);
    k_alloc  <<<(N + 255) / 256, 256, 0, stream>>>(counts, rowstart, cursor, total, N);
    k_scatter<<<(E + N + 255) / 256, 256, 0, stream>>>(ei, cursor, ssrc, E, N);

    k_xform1 <<<nblk64, 128, 0, stream>>>(x, W1, a_src1, a_dst1, h1, alsrc1, aldst1, N);
    k_aggr1  <<<nblkAg, 256, 0, stream>>>(h1, alsrc1, aldst1, b1, rowstart, counts, ssrc, hact, N);
    k_xform2 <<<nblk64, 64, 0, stream>>>(hact, W2, a_src2, a_dst2, h2, alsrc2, aldst2, N);
    k_aggr2  <<<nblkAg, 256, 0, stream>>>(h2, alsrc2, aldst2, b2, rowstart, counts, ssrc, out, N);
}